// Round 1
// baseline (289.360 us; speedup 1.0000x reference)
//
#include <hip/hip_runtime.h>
#include <hip/hip_bf16.h>
#include <math.h>

#define T_TYPES 4
#define NN 8192
#define HD 256
#define DOUT 64

typedef __bf16 bf16_t;
typedef __bf16 bf16x8 __attribute__((ext_vector_type(8)));
typedef float f32x4 __attribute__((ext_vector_type(4)));

// ---------------- workspace layout (bytes) ----------------
#define H0_OFF 0u
#define H1_OFF 16777216u
#define PW_OFF 33554432u
#define TW_OFF 38928384u
#define PS_OFF 38928448u
#define PM_OFF 39190592u
// packed weight element offsets (bf16 elems, base PW_OFF)
#define PW_ELEMS 2686976
#define PW_LAYER(l) (65536 + (l)*1310720)
#define PWL_WB 65536
#define PWL_WC 327680
#define PWL_WD 524288

// =========================================================
// pack fp32 weights -> bf16 in B-fragment-friendly layout [K/8][256][8]
// also computes softmax(trans_arch) and softmax(agg_arch)
// =========================================================
__global__ void pack_kernel(const float* __restrict__ lin1_w,
                            const float* __restrict__ lin_w,
                            const float* __restrict__ rel_lin_w,
                            const float* __restrict__ conv_w,
                            const float* __restrict__ rel_conv_w,
                            const float* __restrict__ trans_arch,
                            const float* __restrict__ agg_arch,
                            bf16_t* __restrict__ pw,
                            float* __restrict__ tws) {
    int idx = blockIdx.x * 256 + threadIdx.x;
    if (blockIdx.x == 0 && threadIdx.x == 0) {
        for (int l = 0; l < 2; ++l) {
            float m = trans_arch[l * 5];
            for (int i = 1; i < 5; ++i) m = fmaxf(m, trans_arch[l * 5 + i]);
            float e[5], s = 0.f;
            for (int i = 0; i < 5; ++i) { e[i] = __expf(trans_arch[l * 5 + i] - m); s += e[i]; }
            for (int i = 0; i < 5; ++i) tws[l * 5 + i] = e[i] / s;
        }
        float m = fmaxf(fmaxf(agg_arch[0], agg_arch[1]), agg_arch[2]);
        float e0 = __expf(agg_arch[0] - m), e1 = __expf(agg_arch[1] - m), e2 = __expf(agg_arch[2] - m);
        float s = e0 + e1 + e2;
        tws[10] = e0 / s; tws[11] = e1 / s; tws[12] = e2 / s;
    }
    if (idx >= PW_ELEMS) return;
    float v;
    if (idx < 65536) {
        int kb = idx >> 11, n = (idx >> 3) & 255, kr = idx & 7, k = kb * 8 + kr;
        v = lin1_w[k * 256 + n];
    } else {
        int r = idx - 65536;
        int l = r / 1310720; r -= l * 1310720;
        if (r < 65536) {
            int kb = r >> 11, n = (r >> 3) & 255, kr = r & 7, k = kb * 8 + kr;
            v = lin_w[(l * 256 + k) * 256 + n];
        } else if (r < 327680) {
            int rr = r - 65536; int t = rr >> 16; rr &= 65535;
            int kb = rr >> 11, n = (rr >> 3) & 255, kr = rr & 7, k = kb * 8 + kr;
            v = rel_lin_w[((l * 4 + t) * 256 + k) * 256 + n];
        } else if (r < 524288) {
            int rr = r - 327680;
            int kb = rr >> 11, n = (rr >> 3) & 255, kr = rr & 7, k = kb * 8 + kr;
            int seg = k >> 8, d = k & 255;
            v = conv_w[((l * 256 + n) * 256 + d) * 3 + seg];
        } else {
            int rr = r - 524288; int t = rr / 196608; rr -= t * 196608;
            int kb = rr >> 11, n = (rr >> 3) & 255, kr = rr & 7, k = kb * 8 + kr;
            int seg = k >> 8, d = k & 255;
            v = rel_conv_w[(((l * 4 + t) * 256 + n) * 256 + d) * 3 + seg];
        }
    }
    pw[idx] = (bf16_t)v;
}

// =========================================================
// lin1: h0 = x @ lin1_w + lin1_b   (fp32 in, bf16 out, no relu)
// 128x128 tile, 4 waves, 4x4 frags of 16x16x32 bf16 MFMA
// =========================================================
__global__ __launch_bounds__(256, 2) void lin1_kernel(
    const float* __restrict__ x, bf16_t* __restrict__ h0,
    const bf16_t* __restrict__ w, const float* __restrict__ b) {
    __shared__ __align__(16) bf16_t lA[128 * 40];
    __shared__ __align__(16) bf16_t lB[4096];
    const int tid = threadIdx.x;
    const int bx = blockIdx.x;
    const int t = bx >> 7, rb = bx & 127, mt = rb >> 1, ct = rb & 1;
    const int m0 = mt * 128, c0 = ct * 128;
    const int lane = tid & 63, wid = tid >> 6;
    const int wm = (wid >> 1) * 64, wn = (wid & 1) * 64;
    const int lrow = lane & 15, lq = lane >> 4;

    f32x4 acc[4][4];
#pragma unroll
    for (int i = 0; i < 4; ++i)
#pragma unroll
        for (int j = 0; j < 4; ++j) acc[i][j] = (f32x4){0.f, 0.f, 0.f, 0.f};

    for (int kt = 0; kt < 8; ++kt) {
        const int k0 = kt * 32;
        __syncthreads();
#pragma unroll
        for (int p = 0; p < 2; ++p) {
            int c = p * 256 + tid;
            {   // A: fp32 -> bf16
                int row = c >> 2, kq = c & 3;
                const float4* s4 = reinterpret_cast<const float4*>(
                    x + ((size_t)(t * NN + m0 + row)) * HD + k0 + kq * 8);
                float4 u0 = s4[0], u1 = s4[1];
                bf16x8 wv;
                wv[0] = (bf16_t)u0.x; wv[1] = (bf16_t)u0.y; wv[2] = (bf16_t)u0.z; wv[3] = (bf16_t)u0.w;
                wv[4] = (bf16_t)u1.x; wv[5] = (bf16_t)u1.y; wv[6] = (bf16_t)u1.z; wv[7] = (bf16_t)u1.w;
                *reinterpret_cast<bf16x8*>(&lA[row * 40 + kq * 8]) = wv;
            }
            {   // B: packed bf16 passthrough
                int coll = c & 127, kq = c >> 7;
                *reinterpret_cast<float4*>(&lB[(kq * 128 + coll) * 8]) =
                    *reinterpret_cast<const float4*>(w + ((size_t)((k0 >> 3) + kq) * 256 + c0 + coll) * 8);
            }
        }
        __syncthreads();
        bf16x8 af[4], bfr[4];
#pragma unroll
        for (int i = 0; i < 4; ++i)
            af[i] = *reinterpret_cast<const bf16x8*>(&lA[(wm + i * 16 + lrow) * 40 + lq * 8]);
#pragma unroll
        for (int j = 0; j < 4; ++j)
            bfr[j] = *reinterpret_cast<const bf16x8*>(&lB[(lq * 128 + wn + j * 16 + lrow) * 8]);
#pragma unroll
        for (int i = 0; i < 4; ++i)
#pragma unroll
            for (int j = 0; j < 4; ++j)
                acc[i][j] = __builtin_amdgcn_mfma_f32_16x16x32_bf16(af[i], bfr[j], acc[i][j], 0, 0, 0);
    }
#pragma unroll
    for (int j = 0; j < 4; ++j) {
        int col = c0 + wn + j * 16 + lrow;
        float bj = b[col];
#pragma unroll
        for (int i = 0; i < 4; ++i)
#pragma unroll
            for (int r = 0; r < 4; ++r) {
                int row = m0 + wm + i * 16 + lq * 4 + r;
                h0[((size_t)t * NN + row) * HD + col] = (bf16_t)(acc[i][j][r] + bj);
            }
    }
}

// =========================================================
// layer: h_out = w0*relu(h@Wlin+b) + w1*relu(h@Wrel[t]+b) +
//        w2*relu(conv3(h)+b) + w3*relu(relconv3[t](h)+b) + w4*h
// conv handled as K=768 GEMM over node-shifted A tiles (zero pad)
// =========================================================
__global__ __launch_bounds__(256, 2) void layer_kernel(
    const bf16_t* __restrict__ hin, bf16_t* __restrict__ hout,
    const bf16_t* __restrict__ lw,
    const float* __restrict__ lin_b, const float* __restrict__ rel_lin_b,
    const float* __restrict__ conv_b, const float* __restrict__ rel_conv_b,
    const float* __restrict__ tw5) {
    __shared__ __align__(16) bf16_t lA[128 * 40];
    __shared__ __align__(16) bf16_t lB[4096];
    const int tid = threadIdx.x;
    const int bx = blockIdx.x;
    const int t = bx >> 7, rb = bx & 127, mt = rb >> 1, ct = rb & 1;
    const int m0 = mt * 128, c0 = ct * 128;
    const int lane = tid & 63, wid = tid >> 6;
    const int wm = (wid >> 1) * 64, wn = (wid & 1) * 64;
    const int lrow = lane & 15, lq = lane >> 4;

    const bf16_t* Wm[4] = { lw, lw + PWL_WB + t * 65536, lw + PWL_WC, lw + PWL_WD + t * 196608 };
    const float* Bm[4] = { lin_b, rel_lin_b + t * 256, conv_b, rel_conv_b + t * 256 };

    f32x4 res[4][4];
#pragma unroll
    for (int i = 0; i < 4; ++i)
#pragma unroll
        for (int j = 0; j < 4; ++j) res[i][j] = (f32x4){0.f, 0.f, 0.f, 0.f};

    for (int mat = 0; mat < 4; ++mat) {
        const int KT = (mat < 2) ? 8 : 24;
        const bf16_t* W = Wm[mat];
        const float wgt = tw5[mat];
        f32x4 acc[4][4];
#pragma unroll
        for (int i = 0; i < 4; ++i)
#pragma unroll
            for (int j = 0; j < 4; ++j) acc[i][j] = (f32x4){0.f, 0.f, 0.f, 0.f};

        for (int kt = 0; kt < KT; ++kt) {
            const int k0 = kt * 32;
            const int seg = k0 >> 8;
            const int koff = k0 & 255;
            const int rowoff = (mat < 2) ? 0 : seg - 1;
            __syncthreads();
#pragma unroll
            for (int p = 0; p < 2; ++p) {
                int c = p * 256 + tid;
                {
                    int row = c >> 2, kq = c & 3;
                    int gr = m0 + row + rowoff;
                    float4 av = make_float4(0.f, 0.f, 0.f, 0.f);
                    if (gr >= 0 && gr < NN)
                        av = *reinterpret_cast<const float4*>(
                            hin + ((size_t)t * NN + gr) * HD + koff + kq * 8);
                    *reinterpret_cast<float4*>(&lA[row * 40 + kq * 8]) = av;
                }
                {
                    int coll = c & 127, kq = c >> 7;
                    *reinterpret_cast<float4*>(&lB[(kq * 128 + coll) * 8]) =
                        *reinterpret_cast<const float4*>(W + ((size_t)((k0 >> 3) + kq) * 256 + c0 + coll) * 8);
                }
            }
            __syncthreads();
            bf16x8 af[4], bfr[4];
#pragma unroll
            for (int i = 0; i < 4; ++i)
                af[i] = *reinterpret_cast<const bf16x8*>(&lA[(wm + i * 16 + lrow) * 40 + lq * 8]);
#pragma unroll
            for (int j = 0; j < 4; ++j)
                bfr[j] = *reinterpret_cast<const bf16x8*>(&lB[(lq * 128 + wn + j * 16 + lrow) * 8]);
#pragma unroll
            for (int i = 0; i < 4; ++i)
#pragma unroll
                for (int j = 0; j < 4; ++j)
                    acc[i][j] = __builtin_amdgcn_mfma_f32_16x16x32_bf16(af[i], bfr[j], acc[i][j], 0, 0, 0);
        }
        const float* bias = Bm[mat];
#pragma unroll
        for (int j = 0; j < 4; ++j) {
            float bj = bias[c0 + wn + j * 16 + lrow];
#pragma unroll
            for (int i = 0; i < 4; ++i)
#pragma unroll
                for (int r = 0; r < 4; ++r) {
                    float v = acc[i][j][r] + bj;
                    v = v > 0.f ? v : 0.f;
                    res[i][j][r] += wgt * v;
                }
        }
    }
    const float w4 = tw5[4];
#pragma unroll
    for (int j = 0; j < 4; ++j) {
        int col = c0 + wn + j * 16 + lrow;
#pragma unroll
        for (int i = 0; i < 4; ++i)
#pragma unroll
            for (int r = 0; r < 4; ++r) {
                int row = m0 + wm + i * 16 + lq * 4 + r;
                size_t idx = ((size_t)t * NN + row) * HD + col;
                float v = res[i][j][r] + w4 * (float)hin[idx];
                hout[idx] = (bf16_t)v;
            }
    }
}

// =========================================================
// reductions + head
// =========================================================
__global__ void reduce1_kernel(const bf16_t* __restrict__ h,
                               float* __restrict__ ps, float* __restrict__ pm) {
    int b = blockIdx.x, c = threadIdx.x;
    float s = 0.f, m = -3.4e38f;
    const bf16_t* p = h + (size_t)b * 128 * HD + c;
#pragma unroll 8
    for (int r = 0; r < 128; ++r) {
        float v = (float)p[(size_t)r * HD];
        s += v; m = fmaxf(m, v);
    }
    ps[b * 256 + c] = s;
    pm[b * 256 + c] = m;
}

__global__ void reduce2_kernel(const float* __restrict__ ps, const float* __restrict__ pm,
                               const float* __restrict__ out_w, const float* __restrict__ out_b,
                               const float* __restrict__ tws, float* __restrict__ out) {
    __shared__ float aggL[256];
    int c = threadIdx.x;
    float s = 0.f, m = -3.4e38f;
    for (int b = 0; b < 256; ++b) { s += ps[b * 256 + c]; m = fmaxf(m, pm[b * 256 + c]); }
    float aw0 = tws[10], aw1 = tws[11], aw2 = tws[12];
    aggL[c] = aw0 * s + aw1 * (s * (1.0f / 32768.f)) + aw2 * m;
    __syncthreads();
    if (c < DOUT) {
        float o = out_b[c];
        for (int e = 0; e < 256; ++e) o += aggL[e] * out_w[e * DOUT + c];
        out[c] = o;
    }
}

extern "C" void kernel_launch(void* const* d_in, const int* in_sizes, int n_in,
                              void* d_out, int out_size, void* d_ws, size_t ws_size,
                              hipStream_t stream) {
    const float* x          = (const float*)d_in[0];
    const float* lin1_w     = (const float*)d_in[1];
    const float* lin1_b     = (const float*)d_in[2];
    const float* lin_w      = (const float*)d_in[3];
    const float* lin_b      = (const float*)d_in[4];
    const float* rel_lin_w  = (const float*)d_in[5];
    const float* rel_lin_b  = (const float*)d_in[6];
    const float* conv_w     = (const float*)d_in[7];
    const float* conv_b     = (const float*)d_in[8];
    const float* rel_conv_w = (const float*)d_in[9];
    const float* rel_conv_b = (const float*)d_in[10];
    const float* out_w      = (const float*)d_in[11];
    const float* out_b      = (const float*)d_in[12];
    const float* trans_arch = (const float*)d_in[13];
    const float* agg_arch   = (const float*)d_in[14];

    char* ws = (char*)d_ws;
    bf16_t* h0 = (bf16_t*)(ws + H0_OFF);
    bf16_t* h1 = (bf16_t*)(ws + H1_OFF);
    bf16_t* pw = (bf16_t*)(ws + PW_OFF);
    float* tws = (float*)(ws + TW_OFF);
    float* ps  = (float*)(ws + PS_OFF);
    float* pm  = (float*)(ws + PM_OFF);
    float* outp = (float*)d_out;

    pack_kernel<<<(PW_ELEMS + 255) / 256, 256, 0, stream>>>(
        lin1_w, lin_w, rel_lin_w, conv_w, rel_conv_w, trans_arch, agg_arch, pw, tws);
    lin1_kernel<<<512, 256, 0, stream>>>(x, h0, pw, lin1_b);
    layer_kernel<<<512, 256, 0, stream>>>(h0, h1, pw + PW_LAYER(0),
        lin_b, rel_lin_b, conv_b, rel_conv_b, tws);
    layer_kernel<<<512, 256, 0, stream>>>(h1, h0, pw + PW_LAYER(1),
        lin_b + 256, rel_lin_b + 1024, conv_b + 256, rel_conv_b + 1024, tws + 5);
    reduce1_kernel<<<256, 256, 0, stream>>>(h0, ps, pm);
    reduce2_kernel<<<1, 256, 0, stream>>>(ps, pm, out_w, out_b, tws, outp);
}

// Round 2
// 272.791 us; speedup vs baseline: 1.0607x; 1.0607x over previous
//
#include <hip/hip_runtime.h>
#include <hip/hip_bf16.h>
#include <math.h>

#define NN 8192
#define HP 8194   // halo: 1 zero guard row at each end of each type
#define HD 256
#define DOUT 64

typedef __bf16 bf16_t;
typedef __bf16 bf16x8 __attribute__((ext_vector_type(8)));
typedef float f32x4 __attribute__((ext_vector_type(4)));

// ---------------- workspace layout (bytes) ----------------
// h buffers: 4 types * 8194 rows * 256 cols * 2B = 16,781,312 B each
#define H0_OFF 0ull
#define H1_OFF 16781312ull
#define PW_OFF 33562624ull
#define TW_OFF 38936576ull
// ps/pm reuse the h1 region (dead after layer1)
#define PS_OFF H1_OFF
#define PM_OFF (H1_OFF + 262144ull)
// packed weight element offsets (bf16 elems, relative to pw)
#define PW_LAYER(l) (65536 + (l)*1310720)
#define PWL_WB 65536
#define PWL_WC 327680
#define PWL_WD 524288

__device__ __forceinline__ void glds16(const void* g, void* l) {
    __builtin_amdgcn_global_load_lds(
        (const __attribute__((address_space(1))) void*)g,
        (__attribute__((address_space(3))) void*)l, 16, 0, 0);
}

// =========================================================
// pack: fp32 weights -> bf16 [K/8][256][8]; softmaxes; zero halo guards
// =========================================================
__global__ __launch_bounds__(256) void pack_kernel(
    const float* __restrict__ lin1_w, const float* __restrict__ lin_w,
    const float* __restrict__ rel_lin_w, const float* __restrict__ conv_w,
    const float* __restrict__ rel_conv_w, const float* __restrict__ trans_arch,
    const float* __restrict__ agg_arch, bf16_t* __restrict__ pw,
    float* __restrict__ tws, bf16_t* __restrict__ h0, bf16_t* __restrict__ h1) {
    __shared__ bf16_t lt[4][2048];
    const int tid = threadIdx.x, lane = tid & 63, wid = tid >> 6;
    const int bx = blockIdx.x;
    if (bx < 88) {
        // lin-family kb-tiles: 352 wave tasks, each 8 k-rows x 256 n
        int task = bx * 4 + wid;
        const float* src; bf16_t* dst; int kb;
        if (task < 32) { src = lin1_w; dst = pw; kb = task; }
        else if (task < 96) { int u = task - 32; int l = u >> 5; kb = u & 31;
            src = lin_w + (size_t)l * 65536; dst = pw + PW_LAYER(l); }
        else { int u = task - 96; int l = u >> 7; int t = (u >> 5) & 3; kb = u & 31;
            src = rel_lin_w + (size_t)(l * 4 + t) * 65536;
            dst = pw + PW_LAYER(l) + PWL_WB + t * 65536; }
        const float4* s4 = (const float4*)(src + (size_t)kb * 8 * 256);
#pragma unroll
        for (int kr = 0; kr < 8; ++kr) {
            float4 v = s4[kr * 64 + lane];
            bf16_t* p = &lt[wid][kr * 256 + lane * 4];
            p[0] = (bf16_t)v.x; p[1] = (bf16_t)v.y; p[2] = (bf16_t)v.z; p[3] = (bf16_t)v.w;
        }
#pragma unroll
        for (int c = 0; c < 4; ++c) {
            bf16x8 wv;
#pragma unroll
            for (int e = 0; e < 8; ++e) wv[e] = lt[wid][e * 256 + lane * 4 + c];
            *(bf16x8*)(dst + (size_t)kb * 2048 + lane * 32 + c * 8) = wv;
        }
    } else if (bx < 728) {
        // conv-family rows: 2560 wave tasks, each one n-row of 768 k
        int task = (bx - 88) * 4 + wid;
        const float* src; bf16_t* dst; int n;
        if (task < 512) { int l = task >> 8; n = task & 255;
            src = conv_w + (size_t)(l * 256 + n) * 768;
            dst = pw + PW_LAYER(l) + PWL_WC; }
        else { int u = task - 512; int l = u >> 10; int t = (u >> 8) & 3; n = u & 255;
            src = rel_conv_w + (size_t)((l * 4 + t) * 256 + n) * 768;
            dst = pw + PW_LAYER(l) + PWL_WD + t * 196608; }
        const float4* s4 = (const float4*)src;
#pragma unroll
        for (int q = 0; q < 3; ++q) {
            float4 v = s4[q * 64 + lane];
            bf16_t* p = &lt[wid][q * 256 + lane * 4];
            p[0] = (bf16_t)v.x; p[1] = (bf16_t)v.y; p[2] = (bf16_t)v.z; p[3] = (bf16_t)v.w;
        }
#pragma unroll
        for (int s = 0; s < 2; ++s) {
            int kb = s * 64 + lane;
            if (kb < 96) {
                bf16x8 wv;
#pragma unroll
                for (int kr = 0; kr < 8; ++kr) {
                    int k = kb * 8 + kr;
                    wv[kr] = lt[wid][(k & 255) * 3 + (k >> 8)];
                }
                *(bf16x8*)(dst + ((size_t)kb * 256 + n) * 8) = wv;
            }
        }
    } else if (bx == 728) {
        // zero guard rows of both h buffers
        int g = tid >> 5, col = (tid & 31) * 8;
        int t = g >> 1, side = g & 1;
        size_t row = (size_t)t * HP + (side ? (HP - 1) : 0);
        bf16x8 z;
#pragma unroll
        for (int e = 0; e < 8; ++e) z[e] = (bf16_t)0.f;
        *(bf16x8*)(h0 + row * HD + col) = z;
        *(bf16x8*)(h1 + row * HD + col) = z;
    } else {
        if (tid == 0) {
            for (int l = 0; l < 2; ++l) {
                float m = trans_arch[l * 5];
                for (int i = 1; i < 5; ++i) m = fmaxf(m, trans_arch[l * 5 + i]);
                float e[5], s = 0.f;
                for (int i = 0; i < 5; ++i) { e[i] = __expf(trans_arch[l * 5 + i] - m); s += e[i]; }
                for (int i = 0; i < 5; ++i) tws[l * 5 + i] = e[i] / s;
            }
            float m = fmaxf(fmaxf(agg_arch[0], agg_arch[1]), agg_arch[2]);
            float e0 = __expf(agg_arch[0] - m), e1 = __expf(agg_arch[1] - m), e2 = __expf(agg_arch[2] - m);
            float s = e0 + e1 + e2;
            tws[10] = e0 / s; tws[11] = e1 / s; tws[12] = e2 / s;
        }
    }
}

// =========================================================
// x (fp32) -> xb (bf16, halo layout, real rows at +1)
// =========================================================
__global__ __launch_bounds__(256) void convert_kernel(
    const float* __restrict__ x, bf16_t* __restrict__ xb) {
    int c = blockIdx.x * 256 + threadIdx.x;      // 0..1048575
    int t = c >> 18;
    int local = c & 262143;
    const float4* s = (const float4*)(x + (size_t)t * NN * HD + (size_t)local * 8);
    float4 u0 = s[0], u1 = s[1];
    bf16x8 wv;
    wv[0] = (bf16_t)u0.x; wv[1] = (bf16_t)u0.y; wv[2] = (bf16_t)u0.z; wv[3] = (bf16_t)u0.w;
    wv[4] = (bf16_t)u1.x; wv[5] = (bf16_t)u1.y; wv[6] = (bf16_t)u1.z; wv[7] = (bf16_t)u1.w;
    *(bf16x8*)(xb + ((size_t)t * HP + 1) * HD + (size_t)local * 8) = wv;
}

// =========================================================
// lin1: h0 = xb @ lin1_w + b (no relu). 128x64 tile, glds staging.
// =========================================================
__global__ __launch_bounds__(256, 3) void lin1_kernel(
    const bf16_t* __restrict__ xb, bf16_t* __restrict__ h0,
    const bf16_t* __restrict__ w, const float* __restrict__ b) {
    __shared__ __align__(16) bf16_t lA[128 * 32];
    __shared__ __align__(16) bf16_t lB[2048];
    const int tid = threadIdx.x, lane = tid & 63, wid = tid >> 6;
    const int bx = blockIdx.x;
    const int t = bx >> 8, rb = bx & 255, mt = rb >> 2, ct = rb & 3;
    const int m0 = mt * 128, c0 = ct * 64;
    const int wm = (wid >> 1) * 64, wn = (wid & 1) * 32;
    const int lrow = lane & 15, lq = lane >> 4;
    const bf16_t* ab = xb + ((size_t)t * HP + 1 + m0) * HD;

    f32x4 acc[4][2];
#pragma unroll
    for (int i = 0; i < 4; ++i)
#pragma unroll
        for (int j = 0; j < 2; ++j) acc[i][j] = (f32x4){0.f, 0.f, 0.f, 0.f};

    for (int kt = 0; kt < 8; ++kt) {
        const int koff = kt * 32;
        __syncthreads();
#pragma unroll
        for (int s = 0; s < 2; ++s) {
            int r = wid * 32 + s * 16 + (lane >> 2);
            glds16(ab + (size_t)r * HD + koff + (lane & 3) * 8, &lA[(wid * 32 + s * 16) * 32]);
        }
        glds16(w + ((size_t)(kt * 4 + (lane & 3)) * 256 + c0 + wid * 16 + (lane >> 2)) * 8,
               &lB[wid * 512]);
        __syncthreads();
        bf16x8 af[4], bfr[2];
#pragma unroll
        for (int i = 0; i < 4; ++i)
            af[i] = *(const bf16x8*)&lA[(wm + i * 16 + lrow) * 32 + lq * 8];
#pragma unroll
        for (int j = 0; j < 2; ++j)
            bfr[j] = *(const bf16x8*)&lB[(wn + j * 16 + lrow) * 32 + lq * 8];
#pragma unroll
        for (int i = 0; i < 4; ++i)
#pragma unroll
            for (int j = 0; j < 2; ++j)
                acc[i][j] = __builtin_amdgcn_mfma_f32_16x16x32_bf16(af[i], bfr[j], acc[i][j], 0, 0, 0);
    }
    bf16_t* op = h0 + ((size_t)t * HP + 1) * HD;
#pragma unroll
    for (int j = 0; j < 2; ++j) {
        int col = c0 + wn + j * 16 + lrow;
        float bj = b[col];
#pragma unroll
        for (int i = 0; i < 4; ++i)
#pragma unroll
            for (int r = 0; r < 4; ++r) {
                int row = m0 + wm + i * 16 + lq * 4 + r;
                op[(size_t)row * HD + col] = (bf16_t)(acc[i][j][r] + bj);
            }
    }
}

// =========================================================
// layer: paired GEMMs sharing the A tile; conv = K=768 over shifted rows
// =========================================================
__global__ __launch_bounds__(256, 2) void layer_kernel(
    const bf16_t* __restrict__ hin, bf16_t* __restrict__ hout,
    const bf16_t* __restrict__ lw,
    const float* __restrict__ lin_b, const float* __restrict__ rel_lin_b,
    const float* __restrict__ conv_b, const float* __restrict__ rel_conv_b,
    const float* __restrict__ tw5) {
    __shared__ __align__(16) bf16_t lA[128 * 32];
    __shared__ __align__(16) bf16_t lB0[2048];
    __shared__ __align__(16) bf16_t lB1[2048];
    const int tid = threadIdx.x, lane = tid & 63, wid = tid >> 6;
    const int bx = blockIdx.x;
    const int t = bx >> 8, rb = bx & 255, mt = rb >> 2, ct = rb & 3;
    const int m0 = mt * 128, c0 = ct * 64;
    const int wm = (wid >> 1) * 64, wn = (wid & 1) * 32;
    const int lrow = lane & 15, lq = lane >> 4;
    const bf16_t* hbase = hin + ((size_t)t * HP + 1) * HD;
    const float w4 = tw5[4];
    const int kt_h = (c0 + wn) >> 5;   // ktile in g=0 that holds this wave's hin cols

    f32x4 res[4][2];
#pragma unroll
    for (int i = 0; i < 4; ++i)
#pragma unroll
        for (int j = 0; j < 2; ++j) res[i][j] = (f32x4){0.f, 0.f, 0.f, 0.f};

    for (int g = 0; g < 2; ++g) {
        const bf16_t* W0 = g ? lw + PWL_WC : lw;
        const bf16_t* W1 = g ? lw + PWL_WD + t * 196608 : lw + PWL_WB + t * 65536;
        const int KT = g ? 24 : 8;
        f32x4 acc0[4][2], acc1[4][2];
#pragma unroll
        for (int i = 0; i < 4; ++i)
#pragma unroll
            for (int j = 0; j < 2; ++j) {
                acc0[i][j] = (f32x4){0.f, 0.f, 0.f, 0.f};
                acc1[i][j] = (f32x4){0.f, 0.f, 0.f, 0.f};
            }
        for (int kt = 0; kt < KT; ++kt) {
            const int seg = g ? (kt >> 3) : 0;
            const int kk = g ? (kt & 7) : kt;
            const int koff = kk * 32;
            const int rowoff = g ? (seg - 1) : 0;
            const int kbg = seg * 32 + kk * 4;
            __syncthreads();
            {   // A: 128 rows x 32 cols bf16, row-major, via glds (halo handles shifts)
                const bf16_t* ag = hbase + (size_t)(m0 + rowoff) * HD + koff;
#pragma unroll
                for (int s = 0; s < 2; ++s) {
                    int r = wid * 32 + s * 16 + (lane >> 2);
                    glds16(ag + (size_t)r * HD + (lane & 3) * 8, &lA[(wid * 32 + s * 16) * 32]);
                }
            }
            {   // B0/B1: [64 col][32 k] bf16 via glds
                size_t be = ((size_t)(kbg + (lane & 3)) * 256 + c0 + wid * 16 + (lane >> 2)) * 8;
                glds16(W0 + be, &lB0[wid * 512]);
                glds16(W1 + be, &lB1[wid * 512]);
            }
            __syncthreads();
            bf16x8 af[4], b0[2], b1[2];
#pragma unroll
            for (int i = 0; i < 4; ++i)
                af[i] = *(const bf16x8*)&lA[(wm + i * 16 + lrow) * 32 + lq * 8];
#pragma unroll
            for (int j = 0; j < 2; ++j) {
                b0[j] = *(const bf16x8*)&lB0[(wn + j * 16 + lrow) * 32 + lq * 8];
                b1[j] = *(const bf16x8*)&lB1[(wn + j * 16 + lrow) * 32 + lq * 8];
            }
#pragma unroll
            for (int i = 0; i < 4; ++i)
#pragma unroll
                for (int j = 0; j < 2; ++j) {
                    acc0[i][j] = __builtin_amdgcn_mfma_f32_16x16x32_bf16(af[i], b0[j], acc0[i][j], 0, 0, 0);
                    acc1[i][j] = __builtin_amdgcn_mfma_f32_16x16x32_bf16(af[i], b1[j], acc1[i][j], 0, 0, 0);
                }
            if (g == 0 && kt == kt_h) {
                // identity term: pull hin tile straight from the staged LDS A
#pragma unroll
                for (int i = 0; i < 4; ++i)
#pragma unroll
                    for (int j = 0; j < 2; ++j)
#pragma unroll
                        for (int r = 0; r < 4; ++r)
                            res[i][j][r] += w4 * (float)lA[(wm + i * 16 + lq * 4 + r) * 32 + j * 16 + lrow];
            }
        }
        const float* b0p = g ? conv_b : lin_b;
        const float* b1p = g ? rel_conv_b + t * 256 : rel_lin_b + t * 256;
        const float wg0 = tw5[g * 2], wg1 = tw5[g * 2 + 1];
#pragma unroll
        for (int j = 0; j < 2; ++j) {
            int col = c0 + wn + j * 16 + lrow;
            float bb0 = b0p[col], bb1 = b1p[col];
#pragma unroll
            for (int i = 0; i < 4; ++i)
#pragma unroll
                for (int r = 0; r < 4; ++r) {
                    float v0 = acc0[i][j][r] + bb0; v0 = v0 > 0.f ? v0 : 0.f;
                    float v1 = acc1[i][j][r] + bb1; v1 = v1 > 0.f ? v1 : 0.f;
                    res[i][j][r] += wg0 * v0 + wg1 * v1;
                }
        }
    }
    bf16_t* op = hout + ((size_t)t * HP + 1) * HD;
#pragma unroll
    for (int j = 0; j < 2; ++j) {
        int col = c0 + wn + j * 16 + lrow;
#pragma unroll
        for (int i = 0; i < 4; ++i)
#pragma unroll
            for (int r = 0; r < 4; ++r) {
                int row = m0 + wm + i * 16 + lq * 4 + r;
                op[(size_t)row * HD + col] = (bf16_t)res[i][j][r];
            }
    }
}

// =========================================================
// reductions + head
// =========================================================
__global__ __launch_bounds__(256) void reduce1_kernel(
    const bf16_t* __restrict__ h, float* __restrict__ ps, float* __restrict__ pm) {
    __shared__ float ss[2048], sm[2048];
    const int tid = threadIdx.x, b = blockIdx.x;
    const int t = b >> 6, rblk = b & 63;
    const int cg = tid & 31, rs = tid >> 5;
    const bf16_t* base = h + ((size_t)t * HP + 1 + rblk * 128) * HD + cg * 8;
    float s[8], m[8];
#pragma unroll
    for (int j = 0; j < 8; ++j) { s[j] = 0.f; m[j] = -3.4e38f; }
    for (int ii = 0; ii < 16; ++ii) {
        bf16x8 v = *(const bf16x8*)(base + (size_t)(rs + ii * 8) * HD);
#pragma unroll
        for (int j = 0; j < 8; ++j) {
            float f = (float)v[j];
            s[j] += f; m[j] = fmaxf(m[j], f);
        }
    }
#pragma unroll
    for (int j = 0; j < 8; ++j) { ss[rs * 256 + cg * 8 + j] = s[j]; sm[rs * 256 + cg * 8 + j] = m[j]; }
    __syncthreads();
    int c = tid;
    float S = 0.f, M = -3.4e38f;
#pragma unroll
    for (int r = 0; r < 8; ++r) { S += ss[r * 256 + c]; M = fmaxf(M, sm[r * 256 + c]); }
    ps[b * 256 + c] = S;
    pm[b * 256 + c] = M;
}

__global__ void reduce2_kernel(const float* __restrict__ ps, const float* __restrict__ pm,
                               const float* __restrict__ out_w, const float* __restrict__ out_b,
                               const float* __restrict__ tws, float* __restrict__ out) {
    __shared__ float aggL[256];
    int c = threadIdx.x;
    float s = 0.f, m = -3.4e38f;
    for (int b = 0; b < 256; ++b) { s += ps[b * 256 + c]; m = fmaxf(m, pm[b * 256 + c]); }
    float aw0 = tws[10], aw1 = tws[11], aw2 = tws[12];
    aggL[c] = aw0 * s + aw1 * (s * (1.0f / 32768.f)) + aw2 * m;
    __syncthreads();
    if (c < DOUT) {
        float o = out_b[c];
        for (int e = 0; e < 256; ++e) o += aggL[e] * out_w[e * DOUT + c];
        out[c] = o;
    }
}

extern "C" void kernel_launch(void* const* d_in, const int* in_sizes, int n_in,
                              void* d_out, int out_size, void* d_ws, size_t ws_size,
                              hipStream_t stream) {
    const float* x          = (const float*)d_in[0];
    const float* lin1_w     = (const float*)d_in[1];
    const float* lin1_b     = (const float*)d_in[2];
    const float* lin_w      = (const float*)d_in[3];
    const float* lin_b      = (const float*)d_in[4];
    const float* rel_lin_w  = (const float*)d_in[5];
    const float* rel_lin_b  = (const float*)d_in[6];
    const float* conv_w     = (const float*)d_in[7];
    const float* conv_b     = (const float*)d_in[8];
    const float* rel_conv_w = (const float*)d_in[9];
    const float* rel_conv_b = (const float*)d_in[10];
    const float* out_w      = (const float*)d_in[11];
    const float* out_b      = (const float*)d_in[12];
    const float* trans_arch = (const float*)d_in[13];
    const float* agg_arch   = (const float*)d_in[14];

    char* ws = (char*)d_ws;
    bf16_t* h0 = (bf16_t*)(ws + H0_OFF);
    bf16_t* h1 = (bf16_t*)(ws + H1_OFF);
    bf16_t* xb = h1;                    // xb shares h1 (dead before layer0 writes h1)
    bf16_t* pw = (bf16_t*)(ws + PW_OFF);
    float* tws = (float*)(ws + TW_OFF);
    float* ps  = (float*)(ws + PS_OFF); // reuse h1 region after layer1
    float* pm  = (float*)(ws + PM_OFF);
    float* outp = (float*)d_out;

    pack_kernel<<<730, 256, 0, stream>>>(lin1_w, lin_w, rel_lin_w, conv_w, rel_conv_w,
                                         trans_arch, agg_arch, pw, tws, h0, h1);
    convert_kernel<<<4096, 256, 0, stream>>>(x, xb);
    lin1_kernel<<<1024, 256, 0, stream>>>(xb, h0, pw, lin1_b);
    layer_kernel<<<1024, 256, 0, stream>>>(h0, h1, pw + PW_LAYER(0),
        lin_b, rel_lin_b, conv_b, rel_conv_b, tws);
    layer_kernel<<<1024, 256, 0, stream>>>(h1, h0, pw + PW_LAYER(1),
        lin_b + 256, rel_lin_b + 1024, conv_b + 256, rel_conv_b + 1024, tws + 5);
    reduce1_kernel<<<256, 256, 0, stream>>>(h0, ps, pm);
    reduce2_kernel<<<1, 256, 0, stream>>>(ps, pm, out_w, out_b, tws, outp);
}

// Round 3
// 233.988 us; speedup vs baseline: 1.2366x; 1.1658x over previous
//
#include <hip/hip_runtime.h>
#include <hip/hip_bf16.h>
#include <math.h>

#define NN 8192
#define HP 8194   // per-type rows incl 1 zero guard row each end
#define HD 256
#define DOUT 64

typedef __bf16 bf16_t;
typedef __bf16 bf16x8 __attribute__((ext_vector_type(8)));
typedef float f32x4 __attribute__((ext_vector_type(4)));

// ---------------- workspace layout (bytes) ----------------
#define H0_OFF 0ull
#define H1_OFF 16781312ull
#define PW_OFF 33562624ull          // 335872 granules * 16B = 5,373,952
#define TW_OFF 38936576ull
#define PS_OFF 38936832ull          // 256KB
#define PM_OFF 39198976ull          // 256KB
// pw granule indices
#define PWG_L1 0
#define PWG_SH(l) (8192 + (l)*32768)
#define PWG_TY(l) (73728 + (l)*131072)

__device__ __forceinline__ void glds16(const void* g, void* l) {
    __builtin_amdgcn_global_load_lds(
        (const __attribute__((address_space(1))) void*)g,
        (__attribute__((address_space(3))) void*)l, 16, 0, 0);
}

__device__ __forceinline__ float frelu(float v) { return v > 0.f ? v : 0.f; }

// =========================================================
// pack: one thread per 16B granule of the B images.
// Image order per (kt,ct) tile == exact LDS layout == contiguous glds.
// granule (s, j2, lq, lrow) holds B[k=kt*32+lq*8+e][n=ct*64+j2*16+lrow]
// =========================================================
__global__ __launch_bounds__(256) void pack_kernel(
    const float* __restrict__ lin1_w, const float* __restrict__ lin_w,
    const float* __restrict__ rel_lin_w, const float* __restrict__ conv_w,
    const float* __restrict__ rel_conv_w, const float* __restrict__ trans_arch,
    const float* __restrict__ agg_arch, bf16_t* __restrict__ pw,
    float* __restrict__ tws, bf16_t* __restrict__ h0, bf16_t* __restrict__ h1) {
    const int bxi = blockIdx.x;
    if (bxi < 1312) {
        int g = bxi * 256 + threadIdx.x;          // 0..335871
        int lrow = g & 15, lq = (g >> 4) & 3, j2 = (g >> 6) & 3;
        float v[8];
        if (g < 8192) {                            // lin1 image
            int ct = (g >> 8) & 3, kt = g >> 10;
            int k = kt * 32 + lq * 8, n = ct * 64 + j2 * 16 + lrow;
#pragma unroll
            for (int e = 0; e < 8; ++e) v[e] = lin1_w[(k + e) * 256 + n];
        } else if (g < 73728) {                    // shared: lin + conv
            int u = g - 8192; int l = u >> 15; int r = u & 32767;
            int s = (r >> 8) & 3, ct = (r >> 10) & 3, kt = r >> 12;
            int k = kt * 32 + lq * 8, n = ct * 64 + j2 * 16 + lrow;
            if (s == 0) {
#pragma unroll
                for (int e = 0; e < 8; ++e) v[e] = lin_w[(l * 256 + k + e) * 256 + n];
            } else {
#pragma unroll
                for (int e = 0; e < 8; ++e)
                    v[e] = conv_w[((l * 256 + n) * 256 + k + e) * 3 + (s - 1)];
            }
        } else {                                   // typed: rel-lin + rel-conv
            int u = g - 73728; int lt = u >> 15; int l = lt >> 2, tt = lt & 3;
            int r = u & 32767;
            int s = (r >> 8) & 3, ct = (r >> 10) & 3, kt = r >> 12;
            int k = kt * 32 + lq * 8, n = ct * 64 + j2 * 16 + lrow;
            if (s == 0) {
#pragma unroll
                for (int e = 0; e < 8; ++e)
                    v[e] = rel_lin_w[((l * 4 + tt) * 256 + k + e) * 256 + n];
            } else {
#pragma unroll
                for (int e = 0; e < 8; ++e)
                    v[e] = rel_conv_w[(((l * 4 + tt) * 256 + n) * 256 + k + e) * 3 + (s - 1)];
            }
        }
        bf16x8 wv;
#pragma unroll
        for (int e = 0; e < 8; ++e) wv[e] = (bf16_t)v[e];
        *(bf16x8*)(pw + (size_t)g * 8) = wv;
    } else if (bxi == 1312) {
        // zero guard rows of both h buffers
        for (int idx = threadIdx.x; idx < 4096; idx += 256) {
            int row_id = idx >> 8, col = idx & 255;
            int buf = row_id >> 3, t_ = (row_id >> 1) & 3, side = row_id & 1;
            bf16_t* hb = buf ? h1 : h0;
            hb[((size_t)t_ * HP + (side ? (HP - 1) : 0)) * HD + col] = (bf16_t)0.f;
        }
    } else {
        if (threadIdx.x == 0) {
            for (int l = 0; l < 2; ++l) {
                float m = trans_arch[l * 5];
                for (int i = 1; i < 5; ++i) m = fmaxf(m, trans_arch[l * 5 + i]);
                float e[5], s = 0.f;
                for (int i = 0; i < 5; ++i) { e[i] = __expf(trans_arch[l * 5 + i] - m); s += e[i]; }
                for (int i = 0; i < 5; ++i) tws[l * 5 + i] = e[i] / s;
            }
            float m = fmaxf(fmaxf(agg_arch[0], agg_arch[1]), agg_arch[2]);
            float e0 = __expf(agg_arch[0] - m), e1 = __expf(agg_arch[1] - m), e2 = __expf(agg_arch[2] - m);
            float s = e0 + e1 + e2;
            tws[10] = e0 / s; tws[11] = e1 / s; tws[12] = e2 / s;
        }
    }
}

__device__ __forceinline__ void load_af(bf16x8 af[4], const bf16_t* lA,
                                        int sh, int wm, int lrow, int lq) {
#pragma unroll
    for (int i = 0; i < 4; ++i)
        af[i] = *(const bf16x8*)&lA[(sh + wm + i * 16 + lrow) * 40 + lq * 8];
}

__device__ __forceinline__ void do_mat(const bf16x8 af[4], const bf16_t* Bb,
                                       int grpbase, int lane, f32x4 acc[4][2]) {
#pragma unroll
    for (int j = 0; j < 2; ++j) {
        bf16x8 bfr = *(const bf16x8*)&Bb[(grpbase + j) * 512 + lane * 8];
#pragma unroll
        for (int i = 0; i < 4; ++i)
            acc[i][j] = __builtin_amdgcn_mfma_f32_16x16x32_bf16(af[i], bfr, acc[i][j], 0, 0, 0);
    }
}

// =========================================================
// lin1 (fused fp32->bf16 convert): h0 = x @ lin1_w + b
// 128x64 tile; A VALU-staged (padded stride 40), B dbuf glds.
// =========================================================
__global__ __launch_bounds__(256, 2) void lin1_kernel(
    const float* __restrict__ x, bf16_t* __restrict__ h0,
    const bf16_t* __restrict__ pwL1, const float* __restrict__ b) {
    __shared__ __align__(16) bf16_t lA[128 * 40];
    __shared__ __align__(16) bf16_t lB[2][2048];
    const int tid = threadIdx.x, lane = tid & 63, wid = tid >> 6;
    const int bx = blockIdx.x;
    const int t = bx >> 8, rb = bx & 255, mt = rb >> 2, ct = rb & 3;
    const int m0 = mt * 128, c0 = ct * 64;
    const int wm = (wid >> 1) * 64, wn = (wid & 1) * 32;
    const int lrow = lane & 15, lq = lane >> 4;
    const int wj2 = wn >> 4;
    const int r0 = tid >> 1, kq0 = (tid & 1) * 2;
    const float* xT = x + (size_t)t * NN * HD + (size_t)(m0 + r0) * HD + kq0 * 8;

    f32x4 acc[4][2];
#pragma unroll
    for (int i = 0; i < 4; ++i)
#pragma unroll
        for (int j = 0; j < 2; ++j) acc[i][j] = (f32x4){0.f, 0.f, 0.f, 0.f};

    float4 xa0, xa1, xa2, xa3;
    {
        const float4* p = (const float4*)(xT);
        xa0 = p[0]; xa1 = p[1]; xa2 = p[2]; xa3 = p[3];
    }
    // B(0)
    {
        const bf16_t* src = pwL1 + (size_t)((0 * 4 + ct) * 4 + wid) * 512 + (size_t)lane * 8;
        glds16(src, &lB[0][wid * 512]);
    }
    for (int kt = 0; kt < 8; ++kt) {
        bf16x8 w0, w1;
        w0[0]=(bf16_t)xa0.x; w0[1]=(bf16_t)xa0.y; w0[2]=(bf16_t)xa0.z; w0[3]=(bf16_t)xa0.w;
        w0[4]=(bf16_t)xa1.x; w0[5]=(bf16_t)xa1.y; w0[6]=(bf16_t)xa1.z; w0[7]=(bf16_t)xa1.w;
        w1[0]=(bf16_t)xa2.x; w1[1]=(bf16_t)xa2.y; w1[2]=(bf16_t)xa2.z; w1[3]=(bf16_t)xa2.w;
        w1[4]=(bf16_t)xa3.x; w1[5]=(bf16_t)xa3.y; w1[6]=(bf16_t)xa3.z; w1[7]=(bf16_t)xa3.w;
        *(bf16x8*)&lA[r0 * 40 + kq0 * 8] = w0;
        *(bf16x8*)&lA[r0 * 40 + kq0 * 8 + 8] = w1;
        if (kt < 7) {
            const float4* p = (const float4*)(xT + (kt + 1) * 32);
            xa0 = p[0]; xa1 = p[1]; xa2 = p[2]; xa3 = p[3];
        }
        __syncthreads();
        if (kt < 7) {
            const bf16_t* src = pwL1 + (size_t)(((kt + 1) * 4 + ct) * 4 + wid) * 512 + (size_t)lane * 8;
            glds16(src, &lB[(kt + 1) & 1][wid * 512]);
        }
        const bf16_t* Bb = lB[kt & 1];
        bf16x8 af[4];
        load_af(af, lA, 0, wm, lrow, lq);
#pragma unroll
        for (int j = 0; j < 2; ++j) {
            bf16x8 bfr = *(const bf16x8*)&Bb[(wj2 + j) * 512 + lane * 8];
#pragma unroll
            for (int i = 0; i < 4; ++i)
                acc[i][j] = __builtin_amdgcn_mfma_f32_16x16x32_bf16(af[i], bfr, acc[i][j], 0, 0, 0);
        }
        __syncthreads();
    }
    size_t obase = (size_t)t * HP * HD + (size_t)(1 + m0) * HD;
#pragma unroll
    for (int j = 0; j < 2; ++j) {
        int col = c0 + wn + j * 16 + lrow;
        float bj = b[col];
#pragma unroll
        for (int i = 0; i < 4; ++i)
#pragma unroll
            for (int r = 0; r < 4; ++r) {
                int orow = wm + i * 16 + lq * 4 + r;
                h0[obase + (size_t)orow * HD + col] = (bf16_t)(acc[i][j][r] + bj);
            }
    }
}

// =========================================================
// layer: all 4 ops in one 8-iteration K loop; conv via row-shifted
// reads of the 130-row haloed A tile. A reg-prefetch, B dbuf glds.
// =========================================================
__global__ __launch_bounds__(256, 2) void layer_kernel(
    const bf16_t* __restrict__ hin, bf16_t* __restrict__ hout,
    const bf16_t* __restrict__ pwS, const bf16_t* __restrict__ pwT,
    const float* __restrict__ lin_b, const float* __restrict__ rel_lin_b,
    const float* __restrict__ conv_b, const float* __restrict__ rel_conv_b,
    const float* __restrict__ tw5) {
    __shared__ __align__(16) bf16_t lA[130 * 40];
    __shared__ __align__(16) bf16_t lB[2][16384];
    const int tid = threadIdx.x, lane = tid & 63, wid = tid >> 6;
    const int bx = blockIdx.x;
    const int t = bx >> 8, rb = bx & 255, mt = rb >> 2, ct = rb & 3;
    const int m0 = mt * 128, c0 = ct * 64;
    const int wm = (wid >> 1) * 64, wn = (wid & 1) * 32;
    const int lrow = lane & 15, lq = lane >> 4;
    const int wj2 = wn >> 4;
    const bf16_t* aG = hin + (size_t)t * HP * HD + (size_t)m0 * HD;  // lds row R ↔ hp row m0+R
    const bf16_t* pwTt = pwT + (size_t)t * 262144;                    // elems: t*32768 granules*8
    const int r0 = tid >> 1, kq0 = (tid & 1) * 2;
    const int r1 = 128 + (tid >> 1);
    const bool tail = (tid < 4);

    f32x4 acc[4][4][2];
#pragma unroll
    for (int m = 0; m < 4; ++m)
#pragma unroll
        for (int i = 0; i < 4; ++i)
#pragma unroll
            for (int j = 0; j < 2; ++j) acc[m][i][j] = (f32x4){0.f, 0.f, 0.f, 0.f};

    bf16x8 pa0, pa1, pb0, pb1;
    pa0 = *(const bf16x8*)(aG + (size_t)r0 * HD + kq0 * 8);
    pa1 = *(const bf16x8*)(aG + (size_t)r0 * HD + kq0 * 8 + 8);
    if (tail) {
        pb0 = *(const bf16x8*)(aG + (size_t)r1 * HD + kq0 * 8);
        pb1 = *(const bf16x8*)(aG + (size_t)r1 * HD + kq0 * 8 + 8);
    }
    // B(0): 32 glds, 8 per wave
#pragma unroll
    for (int q = 0; q < 8; ++q) {
        int tk = wid * 8 + q, half = tk >> 4, grp = tk & 15;
        const bf16_t* src = (half ? pwTt : pwS) + (size_t)((0 * 4 + ct) * 16 + grp) * 512 + (size_t)lane * 8;
        glds16(src, &lB[0][(half * 16 + grp) * 512]);
    }
    for (int kt = 0; kt < 8; ++kt) {
        *(bf16x8*)&lA[r0 * 40 + kq0 * 8] = pa0;
        *(bf16x8*)&lA[r0 * 40 + kq0 * 8 + 8] = pa1;
        if (tail) {
            *(bf16x8*)&lA[r1 * 40 + kq0 * 8] = pb0;
            *(bf16x8*)&lA[r1 * 40 + kq0 * 8 + 8] = pb1;
        }
        if (kt < 7) {
            pa0 = *(const bf16x8*)(aG + (size_t)r0 * HD + (kt + 1) * 32 + kq0 * 8);
            pa1 = *(const bf16x8*)(aG + (size_t)r0 * HD + (kt + 1) * 32 + kq0 * 8 + 8);
            if (tail) {
                pb0 = *(const bf16x8*)(aG + (size_t)r1 * HD + (kt + 1) * 32 + kq0 * 8);
                pb1 = *(const bf16x8*)(aG + (size_t)r1 * HD + (kt + 1) * 32 + kq0 * 8 + 8);
            }
        }
        __syncthreads();
        if (kt < 7) {
            int buf = (kt + 1) & 1;
#pragma unroll
            for (int q = 0; q < 8; ++q) {
                int tk = wid * 8 + q, half = tk >> 4, grp = tk & 15;
                const bf16_t* src = (half ? pwTt : pwS) + (size_t)(((kt + 1) * 4 + ct) * 16 + grp) * 512 + (size_t)lane * 8;
                glds16(src, &lB[buf][(half * 16 + grp) * 512]);
            }
        }
        const bf16_t* Bb = lB[kt & 1];
        bf16x8 af[4];
        load_af(af, lA, 1, wm, lrow, lq);            // center shift
        do_mat(af, Bb, 0 + 0 + wj2, lane, acc[0]);   // lin
        do_mat(af, Bb, 16 + 0 + wj2, lane, acc[1]);  // rel-lin
        do_mat(af, Bb, 0 + 8 + wj2, lane, acc[2]);   // conv tap 1
        do_mat(af, Bb, 16 + 8 + wj2, lane, acc[3]);  // rconv tap 1
        load_af(af, lA, 0, wm, lrow, lq);            // shift -1
        do_mat(af, Bb, 0 + 4 + wj2, lane, acc[2]);   // conv tap 0
        do_mat(af, Bb, 16 + 4 + wj2, lane, acc[3]);
        load_af(af, lA, 2, wm, lrow, lq);            // shift +1
        do_mat(af, Bb, 0 + 12 + wj2, lane, acc[2]);  // conv tap 2
        do_mat(af, Bb, 16 + 12 + wj2, lane, acc[3]);
        __syncthreads();
    }
    const float w0 = tw5[0], w1 = tw5[1], w2 = tw5[2], w3 = tw5[3], w4 = tw5[4];
    const float* rb1 = rel_lin_b + t * 256;
    const float* rb3 = rel_conv_b + t * 256;
    size_t obase = (size_t)t * HP * HD + (size_t)(1 + m0) * HD;
#pragma unroll
    for (int j = 0; j < 2; ++j) {
        int col = c0 + wn + j * 16 + lrow;
        float b0 = lin_b[col], b1 = rb1[col], b2 = conv_b[col], b3 = rb3[col];
#pragma unroll
        for (int i = 0; i < 4; ++i)
#pragma unroll
            for (int r = 0; r < 4; ++r) {
                int orow = wm + i * 16 + lq * 4 + r;
                size_t idx = obase + (size_t)orow * HD + col;
                float v = w0 * frelu(acc[0][i][j][r] + b0)
                        + w1 * frelu(acc[1][i][j][r] + b1)
                        + w2 * frelu(acc[2][i][j][r] + b2)
                        + w3 * frelu(acc[3][i][j][r] + b3)
                        + w4 * (float)hin[idx];
                hout[idx] = (bf16_t)v;
            }
    }
}

// =========================================================
// reductions + head (partials transposed for reduce2 coalescing)
// =========================================================
__global__ __launch_bounds__(256) void reduce1_kernel(
    const bf16_t* __restrict__ h, float* __restrict__ ps, float* __restrict__ pm) {
    __shared__ float ss[2048], sm[2048];
    const int tid = threadIdx.x, b = blockIdx.x;
    const int t = b >> 6, rblk = b & 63;
    const int cg = tid & 31, rs = tid >> 5;
    const bf16_t* base = h + ((size_t)t * HP + 1 + rblk * 128) * HD + cg * 8;
    float s[8], m[8];
#pragma unroll
    for (int j = 0; j < 8; ++j) { s[j] = 0.f; m[j] = -3.4e38f; }
    for (int ii = 0; ii < 16; ++ii) {
        bf16x8 v = *(const bf16x8*)(base + (size_t)(rs + ii * 8) * HD);
#pragma unroll
        for (int j = 0; j < 8; ++j) {
            float f = (float)v[j];
            s[j] += f; m[j] = fmaxf(m[j], f);
        }
    }
#pragma unroll
    for (int j = 0; j < 8; ++j) { ss[rs * 256 + cg * 8 + j] = s[j]; sm[rs * 256 + cg * 8 + j] = m[j]; }
    __syncthreads();
    int c = tid;
    float S = 0.f, M = -3.4e38f;
#pragma unroll
    for (int r = 0; r < 8; ++r) { S += ss[r * 256 + c]; M = fmaxf(M, sm[r * 256 + c]); }
    ps[c * 256 + b] = S;   // transposed
    pm[c * 256 + b] = M;
}

__global__ void reduce2_kernel(const float* __restrict__ ps, const float* __restrict__ pm,
                               const float* __restrict__ out_w, const float* __restrict__ out_b,
                               const float* __restrict__ tws, float* __restrict__ out) {
    __shared__ float aggL[256];
    int c = threadIdx.x;
    float s = 0.f, m = -3.4e38f;
    const float4* p4 = (const float4*)(ps + (size_t)c * 256);
    const float4* q4 = (const float4*)(pm + (size_t)c * 256);
    for (int i = 0; i < 64; ++i) {
        float4 a = p4[i]; s += a.x + a.y + a.z + a.w;
        float4 b = q4[i]; m = fmaxf(m, fmaxf(fmaxf(b.x, b.y), fmaxf(b.z, b.w)));
    }
    float aw0 = tws[10], aw1 = tws[11], aw2 = tws[12];
    aggL[c] = aw0 * s + aw1 * (s * (1.0f / 32768.f)) + aw2 * m;
    __syncthreads();
    if (c < DOUT) {
        float o = out_b[c];
        for (int e = 0; e < 256; ++e) o += aggL[e] * out_w[e * DOUT + c];
        out[c] = o;
    }
}

extern "C" void kernel_launch(void* const* d_in, const int* in_sizes, int n_in,
                              void* d_out, int out_size, void* d_ws, size_t ws_size,
                              hipStream_t stream) {
    const float* x          = (const float*)d_in[0];
    const float* lin1_w     = (const float*)d_in[1];
    const float* lin1_b     = (const float*)d_in[2];
    const float* lin_w      = (const float*)d_in[3];
    const float* lin_b      = (const float*)d_in[4];
    const float* rel_lin_w  = (const float*)d_in[5];
    const float* rel_lin_b  = (const float*)d_in[6];
    const float* conv_w     = (const float*)d_in[7];
    const float* conv_b     = (const float*)d_in[8];
    const float* rel_conv_w = (const float*)d_in[9];
    const float* rel_conv_b = (const float*)d_in[10];
    const float* out_w      = (const float*)d_in[11];
    const float* out_b      = (const float*)d_in[12];
    const float* trans_arch = (const float*)d_in[13];
    const float* agg_arch   = (const float*)d_in[14];

    char* ws = (char*)d_ws;
    bf16_t* h0 = (bf16_t*)(ws + H0_OFF);
    bf16_t* h1 = (bf16_t*)(ws + H1_OFF);
    bf16_t* pw = (bf16_t*)(ws + PW_OFF);
    float* tws = (float*)(ws + TW_OFF);
    float* ps  = (float*)(ws + PS_OFF);
    float* pm  = (float*)(ws + PM_OFF);
    float* outp = (float*)d_out;

    pack_kernel<<<1314, 256, 0, stream>>>(lin1_w, lin_w, rel_lin_w, conv_w, rel_conv_w,
                                          trans_arch, agg_arch, pw, tws, h0, h1);
    lin1_kernel<<<1024, 256, 0, stream>>>(x, h0, pw + (size_t)PWG_L1 * 8, lin1_b);
    layer_kernel<<<1024, 256, 0, stream>>>(h0, h1,
        pw + (size_t)PWG_SH(0) * 8, pw + (size_t)PWG_TY(0) * 8,
        lin_b, rel_lin_b, conv_b, rel_conv_b, tws);
    layer_kernel<<<1024, 256, 0, stream>>>(h1, h0,
        pw + (size_t)PWG_SH(1) * 8, pw + (size_t)PWG_TY(1) * 8,
        lin_b + 256, rel_lin_b + 1024, conv_b + 256, rel_conv_b + 1024, tws + 5);
    reduce1_kernel<<<256, 256, 0, stream>>>(h0, ps, pm);
    reduce2_kernel<<<1, 256, 0, stream>>>(ps, pm, out_w, out_b, tws, outp);
}